// Round 3
// baseline (3512.414 us; speedup 1.0000x reference)
//
#include <hip/hip_runtime.h>
#include <stdint.h>
#include <math.h>

// ---------------------------------------------------------------------------
// RSNN forward, MI355X. EXACT integer GEMM for the recurrent layer:
// weights quantized to 27-bit fixed point (W = round(w*2^27), |W| <= 2^22),
// decomposed into 3 signed base-256 i8 digits; binary activations; three
// mfma_i32_16x16x64_i8 planes accumulate Sigma W_sel with ZERO rounding.
// Digits recombined exactly in double; single fp32 round; all remaining ops
// follow the reference's fp32 program order (deterministic, shared with both
// np and jax refs) -> our trajectory is the center of the refs' noise ball.
// Split-K=2 over 256 blocks: s=0 covers plane0 + plane1[0:24); s=1 covers
// plane1[24:48) + plane2 (each 72 k-slabs of 64).
// ---------------------------------------------------------------------------

#define B_   256
#define T_   50
#define I_   1024
#define H_   2048
#define O_   20
#define KA_  48          // activation k-slabs (K=3072 / 64)
#define KW_  144         // weight k-slabs per n-tile (3 planes x 48)
#define SLAB 5120        // 64 rows x 80 B
#define ROWB 80          // 64 data bytes + 16 pad

typedef __attribute__((ext_vector_type(4))) int intx4;

typedef const __attribute__((address_space(1))) void* gas_t;
typedef __attribute__((address_space(3))) void* las_t;

__device__ __forceinline__ void gl_lds16(const void* g, void* s) {
  __builtin_amdgcn_global_load_lds((gas_t)(uintptr_t)g,
                                   (las_t)(uint32_t)(uintptr_t)s, 16, 0, 0);
}

__device__ __forceinline__ int xtl_off(int b, int k) {  // k in [0,3072)
  return ((b >> 6) * KA_ + (k >> 6)) * SLAB + (b & 63) * ROWB + (k & 63);
}

// ---------------------------------------------------------------------------
// Weight prep: digit p of W(n, kk), kk in [0,3072) = [w_ih | w_hh] row n.
// grid 2048*36 x 256, one byte per thread.
// ---------------------------------------------------------------------------
__global__ void prep_w(const float* __restrict__ w_ih,
                       const float* __restrict__ w_hh,
                       int8_t* __restrict__ Wtl) {
  int blk = blockIdx.x;
  int n = blk / 36, kg = blk % 36;
  int k9 = kg * 256 + (int)threadIdx.x;   // [0, 9216)
  int p = k9 / 3072, kk = k9 % 3072;
  float v = (kk < 1024) ? w_ih[n * I_ + kk] : w_hh[n * H_ + (kk - 1024)];
  long long W = llrint((double)v * 134217728.0);  // * 2^27, |W| <= 2^22
  int c0 = (int)((W + 128) & 255) - 128;
  long long W1 = (W - c0) >> 8;
  int c1 = (int)((W1 + 128) & 255) - 128;
  long long W2 = (W1 - c1) >> 8;
  int dig = (p == 0) ? c0 : (p == 1) ? c1 : (int)W2;
  int slab = (n >> 6) * KW_ + p * KA_ + (kk >> 6);
  Wtl[slab * SLAB + (n & 63) * ROWB + (kk & 63)] = (int8_t)dig;
}

// ---------------------------------------------------------------------------
// Init: zero states, zero spike bytes, pack input t=0 as i8 0/1.
// ---------------------------------------------------------------------------
__global__ void init_k(float* __restrict__ Hm, float* __restrict__ Om,
                       float* __restrict__ Osp, float* __restrict__ Osu,
                       float* __restrict__ Mo, int8_t* __restrict__ Xtl,
                       const float* __restrict__ input) {
  int id = blockIdx.x * 256 + threadIdx.x;
  Hm[id] = 0.f;
  {
    int b = id >> 11, h = id & 2047;
    Xtl[xtl_off(b, I_ + h)] = 0;
  }
  if (id < B_ * I_) {
    int b = id >> 10, i = id & 1023;
    Xtl[xtl_off(b, i)] = input[(b * T_) * I_ + i] > 0.5f ? 1 : 0;
  }
  if (id < B_ * O_) {
    Om[id] = 0.f; Osp[id] = 0.f; Osu[id] = 0.f; Mo[id] = 0.f;
  }
}

// ---------------------------------------------------------------------------
// Output phase for one batch (one block): r = h_spk @ w_ho^T in DOUBLE,
// single fp32 round, then fp32 program-order o_mem/spike/softmax.
// ---------------------------------------------------------------------------
__device__ __forceinline__ void ophase_block(
    int b, const int8_t* __restrict__ Xtl, const float* __restrict__ w_ho,
    const float* __restrict__ tau_o, float* __restrict__ Om,
    float* __restrict__ Osp, float* __restrict__ Osu, float* __restrict__ Mo,
    float* r_lds, float* om_l, float* out, int fin) {
  const int tid = threadIdx.x;
  const int lane = tid & 63, wv = tid >> 6;
  float sv[32];
#pragma unroll
  for (int ii = 0; ii < 32; ++ii)
    sv[ii] = (float)Xtl[xtl_off(b, I_ + lane + ii * 64)];  // exact 0/1
#pragma unroll
  for (int oi = 0; oi < 5; ++oi) {
    int o = wv * 5 + oi;
    const float* wr = w_ho + o * H_;
    double s = 0.0;
#pragma unroll
    for (int ii = 0; ii < 32; ++ii)
      s += (double)sv[ii] * (double)wr[lane + ii * 64];
#pragma unroll
    for (int off = 32; off > 0; off >>= 1) s += __shfl_down(s, off);
    if (lane == 0) r_lds[o] = (float)s;   // single rounding
  }
  __syncthreads();
  if (tid < O_) {
    float rr = -1.0f / tau_o[tid];
    float alpha = (float)exp((double)rr);  // correctly-rounded fp32 exp
    float m = Om[b * O_ + tid] * alpha * (1.0f - Osp[b * O_ + tid]) + r_lds[tid];
    om_l[tid] = m;
  }
  __syncthreads();
  if (tid < O_) {
    float mx = om_l[0];
#pragma unroll
    for (int o = 1; o < O_; ++o) mx = fmaxf(mx, om_l[o]);
    float se = 0.f;
#pragma unroll
    for (int o = 0; o < O_; ++o) se += expf(om_l[o] - mx);
    float m = om_l[tid];
    float sp = (m - 0.3f) > 0.f ? 1.f : 0.f;
    Om[b * O_ + tid] = m;
    Osp[b * O_ + tid] = sp;
    float su = Osu[b * O_ + tid] + sp;
    Osu[b * O_ + tid] = su;
    float mo = Mo[b * O_ + tid] + expf(m - mx) / se;
    Mo[b * O_ + tid] = mo;
    if (fin) {
      out[b * O_ + tid] = su / 50.0f;
      out[B_ * O_ + b * O_ + tid] = mo;
    }
  }
  __syncthreads();
}

// ---------------------------------------------------------------------------
// One K-iteration: stage A+B slabs (global_load_lds x16B), 4 i8 MFMAs.
// ---------------------------------------------------------------------------
#define K_ITER(GA, GB, ACC00, ACC01, ACC10, ACC11)                          \
  {                                                                         \
    const char* ga = (GA);                                                  \
    const char* gb = (GB);                                                  \
    gl_lds16(ga + tid * 16, lds + uni + lane * 16);                         \
    {                                                                       \
      int c = tid + 256;                                                    \
      const char* gp = (c < 320) ? (ga + c * 16) : (gb + (c - 320) * 16);   \
      gl_lds16(gp, lds + 4096 + uni + lane * 16);                           \
    }                                                                       \
    if (tid < 128)                                                          \
      gl_lds16(gb + (tid + 192) * 16, lds + 8192 + uni + lane * 16);        \
    __syncthreads();                                                        \
    intx4 a0 = *(const intx4*)pa0;                                          \
    intx4 a1 = *(const intx4*)pa1;                                          \
    intx4 b0 = *(const intx4*)pb0;                                          \
    intx4 b1 = *(const intx4*)pb1;                                          \
    ACC00 = __builtin_amdgcn_mfma_i32_16x16x64_i8(a0, b0, ACC00, 0, 0, 0);  \
    ACC01 = __builtin_amdgcn_mfma_i32_16x16x64_i8(a0, b1, ACC01, 0, 0, 0);  \
    ACC10 = __builtin_amdgcn_mfma_i32_16x16x64_i8(a1, b0, ACC10, 0, 0, 0);  \
    ACC11 = __builtin_amdgcn_mfma_i32_16x16x64_i8(a1, b1, ACC11, 0, 0, 0);  \
    __syncthreads();                                                        \
  }

// ---------------------------------------------------------------------------
// GEMM step: 256 blocks = (s in {0,1}) x (mt 0..3) x (nt 0..31).
// Block tile 64x64, BK=64 i8, 4 waves 2x2 (wave tile 32x32, 2x2 16x16x64).
// Two accumulator sets (digit-weight differs between the block's segments).
// Also runs ophase(t-1) (block j -> batch j) when do_o.
// ---------------------------------------------------------------------------
__global__ __launch_bounds__(256) void gemm_step(
    const int8_t* __restrict__ Xtl, const int8_t* __restrict__ Wtl,
    double* __restrict__ P, const float* __restrict__ w_ho,
    const float* __restrict__ tau_o, float* __restrict__ Om,
    float* __restrict__ Osp, float* __restrict__ Osu, float* __restrict__ Mo,
    int do_o) {
  __shared__ __align__(16) char lds[10240];
  __shared__ float r_lds[O_];
  __shared__ float om_l[O_];

  const int j = blockIdx.x;
  if (do_o)
    ophase_block(j, Xtl, w_ho, tau_o, Om, Osp, Osu, Mo, r_lds, om_l, nullptr, 0);

  const int nt = j & 31, mt = (j >> 5) & 3, s = j >> 7;
  const int tid = threadIdx.x;
  const int lane = tid & 63, wv = tid >> 6;
  const int wm = wv >> 1, wn = wv & 1;
  const int r = lane & 15, g4 = lane >> 4;

  const char* Abase = (const char*)Xtl + (mt * KA_) * SLAB;
  const char* Bbase = (const char*)Wtl + (nt * KW_ + s * 72) * SLAB;

  const char* pa0 = lds + ((wm * 32 + r) * ROWB + g4 * 16);
  const char* pa1 = pa0 + 16 * ROWB;
  const char* pb0 = lds + SLAB + ((wn * 32 + r) * ROWB + g4 * 16);
  const char* pb1 = pb0 + 16 * ROWB;
  const int uni = wv * 1024;

  intx4 aA00 = {0,0,0,0}, aA01 = {0,0,0,0}, aA10 = {0,0,0,0}, aA11 = {0,0,0,0};
  intx4 aB00 = {0,0,0,0}, aB01 = {0,0,0,0}, aB10 = {0,0,0,0}, aB11 = {0,0,0,0};

  // segment A: s=0 -> plane0 (48 slabs, akx=kx); s=1 -> plane1[24:48) (akx=24+kx)
  const int lenA = s ? 24 : 48;
  const int aoffA = s ? 24 : 0;
  for (int kx = 0; kx < lenA; ++kx) {
    K_ITER(Abase + (aoffA + kx) * SLAB, Bbase + kx * SLAB, aA00, aA01, aA10, aA11);
  }
  // segment B: s=0 -> plane1[0:24) ; s=1 -> plane2 (48 slabs); akx=kx both
  const int lenB = 72 - lenA;
  const char* BbaseB = Bbase + lenA * SLAB;
  for (int kx = 0; kx < lenB; ++kx) {
    K_ITER(Abase + kx * SLAB, BbaseB + kx * SLAB, aB00, aB01, aB10, aB11);
  }

  // epilogue: exact digit recombination in double. D: col=lane&15, row=quad*4+jj
  const double wA = s ? 256.0 : 1.0;
  const double wB = s ? 65536.0 : 256.0;
  double* Pp = P + s * (B_ * H_);
  const int b0r = mt * 64 + wm * 32 + g4 * 4;
  const int h0 = nt * 64 + wn * 32 + r;
#pragma unroll
  for (int jj = 0; jj < 4; ++jj) {
    Pp[(b0r + jj) * H_ + h0]           = wA * (double)aA00[jj] + wB * (double)aB00[jj];
    Pp[(b0r + jj) * H_ + h0 + 16]      = wA * (double)aA01[jj] + wB * (double)aB01[jj];
    Pp[(b0r + 16 + jj) * H_ + h0]      = wA * (double)aA10[jj] + wB * (double)aB10[jj];
    Pp[(b0r + 16 + jj) * H_ + h0 + 16] = wA * (double)aA11[jj] + wB * (double)aB11[jj];
  }
}

// ---------------------------------------------------------------------------
// Spike/decay/pack: S = P0+P1 (exact integer in double); single fp32 round
// of S*2^-27; then fp32 program-order decay + threshold. Packs input t+1.
// ---------------------------------------------------------------------------
__global__ void spike_pack(const double* __restrict__ P, float* __restrict__ Hm,
                           int8_t* __restrict__ Xtl,
                           const float* __restrict__ tau_h,
                           const float* __restrict__ input, int t) {
  int blk = blockIdx.x;
  int b = blk >> 3, hc = blk & 7;
  int h = hc * 256 + threadIdx.x;
  int idx = b * H_ + h;
  double S = P[idx] + P[B_ * H_ + idx];           // exact (integers < 2^53)
  float M = (float)(S * 7.450580596923828125e-9); // * 2^-27, single rounding
  float sp = (float)Xtl[xtl_off(b, I_ + h)];
  float hprev = Hm[idx];
  float rr = -1.0f / tau_h[h];
  float alpha = (float)exp((double)rr);
  float hm = M + hprev * alpha * (1.0f - sp);     // fp32 program order
  int8_t spk = (hm - 0.3f) > 0.f ? 1 : 0;
  Hm[idx] = hm;
  Xtl[xtl_off(b, I_ + h)] = spk;
  if (hc < 4 && (t + 1) < T_) {
    Xtl[xtl_off(b, h)] = input[(b * T_ + t + 1) * I_ + h] > 0.5f ? 1 : 0;
  }
}

// ---------------------------------------------------------------------------
// Final ophase (t=49) + output write.
// ---------------------------------------------------------------------------
__global__ void final_k(const int8_t* __restrict__ Xtl,
                        const float* __restrict__ w_ho,
                        const float* __restrict__ tau_o, float* __restrict__ Om,
                        float* __restrict__ Osp, float* __restrict__ Osu,
                        float* __restrict__ Mo, float* __restrict__ out) {
  __shared__ float r_lds[O_];
  __shared__ float om_l[O_];
  ophase_block(blockIdx.x, Xtl, w_ho, tau_o, Om, Osp, Osu, Mo, r_lds, om_l, out, 1);
}

// ---------------------------------------------------------------------------
extern "C" void kernel_launch(void* const* d_in, const int* in_sizes, int n_in,
                              void* d_out, int out_size, void* d_ws, size_t ws_size,
                              hipStream_t stream) {
  const float* input = (const float*)d_in[0];
  const float* w_ih  = (const float*)d_in[1];
  const float* w_hh  = (const float*)d_in[2];
  const float* w_ho  = (const float*)d_in[3];
  const float* tau_h = (const float*)d_in[4];
  const float* tau_o = (const float*)d_in[5];

  char* ws = (char*)d_ws;
  // layout (bytes):
  // Wtl: 32*144*5120      = 23,592,960
  // Xtl:  4* 48*5120      =    983,040   -> 24,576,000
  // P  : 2*256*2048*8     =  8,388,608   -> 32,964,608
  // Hm : 256*2048*4       =  2,097,152   -> 35,061,760
  // Om/Osp/Osu/Mo: 4 x 20,480
  int8_t* Wtl = (int8_t*)(ws);
  int8_t* Xtl = (int8_t*)(ws + 23592960);
  double* P   = (double*)(ws + 24576000);
  float* Hm   = (float*)(ws + 32964608);
  float* Om   = (float*)(ws + 35061760);
  float* Osp  = (float*)(ws + 35082240);
  float* Osu  = (float*)(ws + 35102720);
  float* Mo   = (float*)(ws + 35123200);
  float* out  = (float*)d_out;

  prep_w<<<2048 * 36, 256, 0, stream>>>(w_ih, w_hh, Wtl);
  init_k<<<2048, 256, 0, stream>>>(Hm, Om, Osp, Osu, Mo, Xtl, input);
  for (int t = 0; t < T_; ++t) {
    gemm_step<<<256, 256, 0, stream>>>(Xtl, Wtl, P, w_ho, tau_o, Om, Osp, Osu,
                                       Mo, t > 0 ? 1 : 0);
    spike_pack<<<2048, 256, 0, stream>>>(P, Hm, Xtl, tau_h, input, t);
  }
  final_k<<<256, 256, 0, stream>>>(Xtl, w_ho, tau_o, Om, Osp, Osu, Mo, out);
}

// Round 4
// 1885.722 us; speedup vs baseline: 1.8626x; 1.8626x over previous
//
#include <hip/hip_runtime.h>
#include <stdint.h>
#include <math.h>

// ---------------------------------------------------------------------------
// RSNN forward, MI355X. EXACT integer GEMM (27-bit fixed-point weights, 3
// signed base-256 i8 digit planes, binary activations, i32 MFMA accumulate,
// exact recombination, single fp32 round) — numerics identical to round 3
// (passed, absmax 0.0156). Speed restructure:
//  * NO LDS / NO barriers in the GEMM K-loop: A and B MFMA fragments are
//    16 rows x 16 B = contiguous 1 KB per wave in the unpadded tiled images,
//    loaded straight to VGPRs (global_load_dwordx4), software-pipelined via
//    compiler vmcnt(N) — removes the per-iter vmcnt(0)+barrier drain that
//    made round 3 latency-serialized (70 us/step at 1 block/CU).
//  * Grid 768 (3 blocks/CU): slice = (plane p, k-half s), 24 k-slabs each;
//    one i32 acc set per block; 6 partial planes recombined in spike_pack.
//  * XCD swizzle: the 8 (mt,s) blocks sharing weight panel (p,nt) share
//    blockIdx%8 -> same XCD -> 2.3 MB weight set stays L2-resident across
//    all 50 steps (weights static).
// ---------------------------------------------------------------------------

#define B_   256
#define T_   50
#define I_   1024
#define H_   2048
#define O_   20
#define KA_  48          // activation k-slabs (K=3072 / 64)
#define KW_  144         // weight k-slabs per n-tile (3 planes x 48)
#define SLAB 4096        // 64 rows x 64 B (unpadded)
#define BH   (B_ * H_)

typedef __attribute__((ext_vector_type(4))) int intx4;

__device__ __forceinline__ int xtl_off(int b, int k) {  // k in [0,3072)
  return ((b >> 6) * KA_ + (k >> 6)) * SLAB + (b & 63) * 64 + (k & 63);
}

// ---------------------------------------------------------------------------
// Weight prep: digit p of W(n, kk), kk in [0,3072) = [w_ih | w_hh] row n.
// ---------------------------------------------------------------------------
__global__ void prep_w(const float* __restrict__ w_ih,
                       const float* __restrict__ w_hh,
                       int8_t* __restrict__ Wtl) {
  int blk = blockIdx.x;
  int n = blk / 36, kg = blk % 36;
  int k9 = kg * 256 + (int)threadIdx.x;   // [0, 9216)
  int p = k9 / 3072, kk = k9 % 3072;
  float v = (kk < 1024) ? w_ih[n * I_ + kk] : w_hh[n * H_ + (kk - 1024)];
  long long W = llrint((double)v * 134217728.0);  // * 2^27, |W| <= 2^22
  int c0 = (int)((W + 128) & 255) - 128;
  long long W1 = (W - c0) >> 8;
  int c1 = (int)((W1 + 128) & 255) - 128;
  long long W2 = (W1 - c1) >> 8;
  int dig = (p == 0) ? c0 : (p == 1) ? c1 : (int)W2;
  int slab = (n >> 6) * KW_ + p * KA_ + (kk >> 6);
  Wtl[slab * SLAB + (n & 63) * 64 + (kk & 63)] = (int8_t)dig;
}

// ---------------------------------------------------------------------------
// Init: zero states, zero spike bytes, pack input t=0 as i8 0/1.
// ---------------------------------------------------------------------------
__global__ void init_k(float* __restrict__ Hm, float* __restrict__ Om,
                       float* __restrict__ Osp, float* __restrict__ Osu,
                       float* __restrict__ Mo, int8_t* __restrict__ Xtl,
                       const float* __restrict__ input) {
  int id = blockIdx.x * 256 + threadIdx.x;
  Hm[id] = 0.f;
  {
    int b = id >> 11, h = id & 2047;
    Xtl[xtl_off(b, I_ + h)] = 0;
  }
  if (id < B_ * I_) {
    int b = id >> 10, i = id & 1023;
    Xtl[xtl_off(b, i)] = input[(b * T_) * I_ + i] > 0.5f ? 1 : 0;
  }
  if (id < B_ * O_) {
    Om[id] = 0.f; Osp[id] = 0.f; Osu[id] = 0.f; Mo[id] = 0.f;
  }
}

// ---------------------------------------------------------------------------
// Output phase for one batch (one block): r = h_spk @ w_ho^T in DOUBLE,
// single fp32 round, then fp32 program-order o_mem/spike/softmax.
// ---------------------------------------------------------------------------
__device__ __forceinline__ void ophase_block(
    int b, const int8_t* __restrict__ Xtl, const float* __restrict__ w_ho,
    const float* __restrict__ tau_o, float* __restrict__ Om,
    float* __restrict__ Osp, float* __restrict__ Osu, float* __restrict__ Mo,
    float* r_lds, float* om_l, float* out, int fin) {
  const int tid = threadIdx.x;
  const int lane = tid & 63, wv = tid >> 6;
  float sv[32];
#pragma unroll
  for (int ii = 0; ii < 32; ++ii)
    sv[ii] = (float)Xtl[xtl_off(b, I_ + lane + ii * 64)];  // exact 0/1
#pragma unroll
  for (int oi = 0; oi < 5; ++oi) {
    int o = wv * 5 + oi;
    const float* wr = w_ho + o * H_;
    double s = 0.0;
#pragma unroll
    for (int ii = 0; ii < 32; ++ii)
      s += (double)sv[ii] * (double)wr[lane + ii * 64];
#pragma unroll
    for (int off = 32; off > 0; off >>= 1) s += __shfl_down(s, off);
    if (lane == 0) r_lds[o] = (float)s;   // single rounding
  }
  __syncthreads();
  if (tid < O_) {
    float rr = -1.0f / tau_o[tid];
    float alpha = (float)exp((double)rr);
    float m = Om[b * O_ + tid] * alpha * (1.0f - Osp[b * O_ + tid]) + r_lds[tid];
    om_l[tid] = m;
  }
  __syncthreads();
  if (tid < O_) {
    float mx = om_l[0];
#pragma unroll
    for (int o = 1; o < O_; ++o) mx = fmaxf(mx, om_l[o]);
    float se = 0.f;
#pragma unroll
    for (int o = 0; o < O_; ++o) se += expf(om_l[o] - mx);
    float m = om_l[tid];
    float sp = (m - 0.3f) > 0.f ? 1.f : 0.f;
    Om[b * O_ + tid] = m;
    Osp[b * O_ + tid] = sp;
    float su = Osu[b * O_ + tid] + sp;
    Osu[b * O_ + tid] = su;
    float mo = Mo[b * O_ + tid] + expf(m - mx) / se;
    Mo[b * O_ + tid] = mo;
    if (fin) {
      out[b * O_ + tid] = su / 50.0f;
      out[B_ * O_ + b * O_ + tid] = mo;
    }
  }
  __syncthreads();
}

// ---------------------------------------------------------------------------
// GEMM step: 768 blocks. Swizzled decode: group g=(p,nt) shares blockIdx%8
// (same XCD); member m=(mt,s). Block tile 64x64, 4 waves 2x2 (wave 32x32,
// 2x2 mfma 16x16x64 i8). Direct global->VGPR fragments, no LDS, no barriers.
// Blocks j<256 also run ophase(t-1) for batch j when do_o.
// ---------------------------------------------------------------------------
__global__ __launch_bounds__(256) void gemm_step(
    const int8_t* __restrict__ Xtl, const int8_t* __restrict__ Wtl,
    int* __restrict__ P, const float* __restrict__ w_ho,
    const float* __restrict__ tau_o, float* __restrict__ Om,
    float* __restrict__ Osp, float* __restrict__ Osu, float* __restrict__ Mo,
    int do_o) {
  __shared__ float r_lds[O_];
  __shared__ float om_l[O_];
  const int j = blockIdx.x;
  if (do_o && j < B_)
    ophase_block(j, Xtl, w_ho, tau_o, Om, Osp, Osu, Mo, r_lds, om_l, nullptr, 0);

  const int g = ((j >> 6) << 3) | (j & 7);   // weight group [0,96)
  const int m = (j >> 3) & 7;                // member [0,8)
  const int p = g >> 5, nt = g & 31;
  const int mt = m >> 1, s = m & 1;

  const int tid = threadIdx.x;
  const int l = tid & 63, wv = tid >> 6;
  const int wm = wv >> 1, wn = wv & 1;
  const int r = l & 15, q = l >> 4;

  const int8_t* pa = Xtl + (size_t)(mt * KA_ + s * 24) * SLAB +
                     (wm * 32 + r) * 64 + q * 16;
  const int8_t* pb = Wtl + (size_t)(nt * KW_ + p * KA_ + s * 24) * SLAB +
                     (wn * 32 + r) * 64 + q * 16;

  intx4 c00 = {0,0,0,0}, c01 = {0,0,0,0}, c10 = {0,0,0,0}, c11 = {0,0,0,0};
  intx4 a0 = *(const intx4*)pa,          a1 = *(const intx4*)(pa + 1024);
  intx4 b0 = *(const intx4*)pb,          b1 = *(const intx4*)(pb + 1024);

#pragma unroll 4
  for (int kx = 0; kx < 24; ++kx) {
    const int kn = (kx < 23) ? (kx + 1) : 23;   // clamp: last iter reloads
    const int8_t* qa = pa + kn * SLAB;
    const int8_t* qb = pb + kn * SLAB;
    intx4 na0 = *(const intx4*)qa, na1 = *(const intx4*)(qa + 1024);
    intx4 nb0 = *(const intx4*)qb, nb1 = *(const intx4*)(qb + 1024);
    c00 = __builtin_amdgcn_mfma_i32_16x16x64_i8(a0, b0, c00, 0, 0, 0);
    c01 = __builtin_amdgcn_mfma_i32_16x16x64_i8(a0, b1, c01, 0, 0, 0);
    c10 = __builtin_amdgcn_mfma_i32_16x16x64_i8(a1, b0, c10, 0, 0, 0);
    c11 = __builtin_amdgcn_mfma_i32_16x16x64_i8(a1, b1, c11, 0, 0, 0);
    a0 = na0; a1 = na1; b0 = nb0; b1 = nb1;
  }

  // epilogue: D col=lane&15, row=quad*4+jj. i32 partial plane (p,s).
  int* Pp = P + (p * 2 + s) * BH;
  const int b0r = mt * 64 + wm * 32 + q * 4;
  const int h0 = nt * 64 + wn * 32 + r;
#pragma unroll
  for (int jj = 0; jj < 4; ++jj) {
    Pp[(b0r + jj) * H_ + h0]           = c00[jj];
    Pp[(b0r + jj) * H_ + h0 + 16]      = c01[jj];
    Pp[(b0r + 16 + jj) * H_ + h0]      = c10[jj];
    Pp[(b0r + 16 + jj) * H_ + h0 + 16] = c11[jj];
  }
}

// ---------------------------------------------------------------------------
// Spike/decay/pack: S = sum of digit planes (exact int64); single fp32 round
// of S*2^-27; fp32 program-order decay + threshold. Packs input t+1.
// ---------------------------------------------------------------------------
__global__ void spike_pack(const int* __restrict__ P, float* __restrict__ Hm,
                           int8_t* __restrict__ Xtl,
                           const float* __restrict__ tau_h,
                           const float* __restrict__ input, int t) {
  int blk = blockIdx.x;
  int b = blk >> 3, hc = blk & 7;
  int h = hc * 256 + threadIdx.x;
  int idx = b * H_ + h;
  int v0 = P[idx] + P[BH + idx];               // plane0 (weight 1)
  int v1 = P[2 * BH + idx] + P[3 * BH + idx];  // plane1 (weight 256)
  int v2 = P[4 * BH + idx] + P[5 * BH + idx];  // plane2 (weight 65536)
  long long S = (long long)v0 + 256LL * (long long)v1 + 65536LL * (long long)v2;
  float M = (float)((double)S * 7.450580596923828125e-9);  // * 2^-27
  float sp = (float)Xtl[xtl_off(b, I_ + h)];
  float hprev = Hm[idx];
  float rr = -1.0f / tau_h[h];
  float alpha = (float)exp((double)rr);
  float hm = M + hprev * alpha * (1.0f - sp);  // fp32 program order
  int8_t spk = (hm - 0.3f) > 0.f ? 1 : 0;
  Hm[idx] = hm;
  Xtl[xtl_off(b, I_ + h)] = spk;
  if (hc < 4 && (t + 1) < T_) {
    Xtl[xtl_off(b, h)] = input[(b * T_ + t + 1) * I_ + h] > 0.5f ? 1 : 0;
  }
}

// ---------------------------------------------------------------------------
// Final ophase (t=49) + output write.
// ---------------------------------------------------------------------------
__global__ void final_k(const int8_t* __restrict__ Xtl,
                        const float* __restrict__ w_ho,
                        const float* __restrict__ tau_o, float* __restrict__ Om,
                        float* __restrict__ Osp, float* __restrict__ Osu,
                        float* __restrict__ Mo, float* __restrict__ out) {
  __shared__ float r_lds[O_];
  __shared__ float om_l[O_];
  ophase_block(blockIdx.x, Xtl, w_ho, tau_o, Om, Osp, Osu, Mo, r_lds, om_l, out, 1);
}

// ---------------------------------------------------------------------------
extern "C" void kernel_launch(void* const* d_in, const int* in_sizes, int n_in,
                              void* d_out, int out_size, void* d_ws, size_t ws_size,
                              hipStream_t stream) {
  const float* input = (const float*)d_in[0];
  const float* w_ih  = (const float*)d_in[1];
  const float* w_hh  = (const float*)d_in[2];
  const float* w_ho  = (const float*)d_in[3];
  const float* tau_h = (const float*)d_in[4];
  const float* tau_o = (const float*)d_in[5];

  char* ws = (char*)d_ws;
  // layout (bytes):
  // Wtl: 32*144*4096 = 18,874,368
  // Xtl:  4* 48*4096 =    786,432  -> 19,660,800
  // P  : 6*256*2048*4 = 12,582,912 -> 32,243,712
  // Hm : 256*2048*4   =  2,097,152 -> 34,340,864
  // Om/Osp/Osu/Mo: 4 x 20,480
  int8_t* Wtl = (int8_t*)(ws);
  int8_t* Xtl = (int8_t*)(ws + 18874368);
  int*    P   = (int*)(ws + 19660800);
  float*  Hm  = (float*)(ws + 32243712);
  float*  Om  = (float*)(ws + 34340864);
  float*  Osp = (float*)(ws + 34361344);
  float*  Osu = (float*)(ws + 34381824);
  float*  Mo  = (float*)(ws + 34402304);
  float*  out = (float*)d_out;

  prep_w<<<2048 * 36, 256, 0, stream>>>(w_ih, w_hh, Wtl);
  init_k<<<2048, 256, 0, stream>>>(Hm, Om, Osp, Osu, Mo, Xtl, input);
  for (int t = 0; t < T_; ++t) {
    gemm_step<<<768, 256, 0, stream>>>(Xtl, Wtl, P, w_ho, tau_o, Om, Osp, Osu,
                                       Mo, t > 0 ? 1 : 0);
    spike_pack<<<2048, 256, 0, stream>>>(P, Hm, Xtl, tau_h, input, t);
  }
  final_k<<<256, 256, 0, stream>>>(Xtl, w_ho, tau_o, Om, Osp, Osu, Mo, out);
}

// Round 5
// 1852.234 us; speedup vs baseline: 1.8963x; 1.0181x over previous
//
#include <hip/hip_runtime.h>
#include <stdint.h>
#include <math.h>

// ---------------------------------------------------------------------------
// RSNN forward, MI355X. EXACT integer GEMM (27-bit fixed-point weights, 3
// signed base-256 i8 digit planes, binary activations, i32 MFMA accumulate,
// exact recombination, single fp32 round). Numerics bit-identical to rounds
// 3/4 (passed, absmax 0.0156).
// Round-5 speed restructure:
//  * Wave tile 64x32 (8 mfma_i32_16x16x64_i8 from 4 A-frags + 2 B-frags):
//    43.7 OPS per L1 byte (was 32) -> L1-BW floor ~5.6 us/step.
//  * Block tile 128x64 (4 waves 2x2), grid = 2mt x 32nt x 3p x 4ks = 768
//    blocks = exactly 3 blocks/CU; 12 K-iters of K=64 per block.
//  * P = 12 i32 partial planes (p,ks); spike_pack sums them exactly.
//  * XCD swizzle: 8 blocks sharing weight panel (p,nt) share blockIdx%8 ->
//    per-XCD 2.36 MB weight set stays L2-resident across all 50 steps.
//  * prep_w: pure-fp32 digit extraction (rintf exact for |W|<=2^22),
//    float4 in / packed 4-byte out.
//  * alpha tables precomputed once (same double-exp formula -> bit-identical).
// ---------------------------------------------------------------------------

#define B_   256
#define T_   50
#define I_   1024
#define H_   2048
#define O_   20
#define KA_  48          // activation k-slabs (K=3072 / 64)
#define KW_  144         // weight k-slabs per n-tile (3 planes x 48)
#define SLAB 4096        // 64 rows x 64 B (unpadded)
#define BH   (B_ * H_)

typedef __attribute__((ext_vector_type(4))) int intx4;

__device__ __forceinline__ int xtl_off(int b, int k) {  // k in [0,3072)
  return ((b >> 6) * KA_ + (k >> 6)) * SLAB + (b & 63) * 64 + (k & 63);
}

// ---------------------------------------------------------------------------
// Weight prep: 4 consecutive digits of W(n, kk..kk+3), packed 4B store.
// grid 2048*9 x 256.
// ---------------------------------------------------------------------------
__device__ __forceinline__ int digit_of(float v, int p) {
  int W = (int)rintf(v * 134217728.0f);   // exact: |W| <= 2^22
  int c0 = ((W + 128) & 255) - 128;
  int W1 = (W - c0) >> 8;
  int c1 = ((W1 + 128) & 255) - 128;
  int W2 = (W1 - c1) >> 8;
  return (p == 0) ? c0 : (p == 1) ? c1 : W2;
}

__global__ void prep_w(const float* __restrict__ w_ih,
                       const float* __restrict__ w_hh,
                       int8_t* __restrict__ Wtl) {
  int blk = blockIdx.x;
  int n = blk / 9, kg = blk % 9;
  int k9 = (kg * 256 + (int)threadIdx.x) * 4;   // [0, 9216), 4-aligned
  int p = k9 / 3072, kk = k9 % 3072;            // 4 elems same plane/side
  const float* src = (kk < 1024) ? (w_ih + n * I_ + kk)
                                 : (w_hh + n * H_ + (kk - 1024));
  float4 v = *(const float4*)src;
  int d0 = digit_of(v.x, p) & 255;
  int d1 = digit_of(v.y, p) & 255;
  int d2 = digit_of(v.z, p) & 255;
  int d3 = digit_of(v.w, p) & 255;
  int packed = d0 | (d1 << 8) | (d2 << 16) | (d3 << 24);
  int slab = (n >> 6) * KW_ + p * KA_ + (kk >> 6);
  *(int*)(Wtl + slab * SLAB + (n & 63) * 64 + (kk & 63)) = packed;
}

// ---------------------------------------------------------------------------
// Init: zero states, zero spike bytes, pack input t=0, alpha tables.
// ---------------------------------------------------------------------------
__global__ void init_k(float* __restrict__ Hm, float* __restrict__ Om,
                       float* __restrict__ Osp, float* __restrict__ Osu,
                       float* __restrict__ Mo, int8_t* __restrict__ Xtl,
                       const float* __restrict__ input,
                       const float* __restrict__ tau_h,
                       const float* __restrict__ tau_o,
                       float* __restrict__ AlphaH, float* __restrict__ AlphaO) {
  int id = blockIdx.x * 256 + threadIdx.x;
  Hm[id] = 0.f;
  {
    int b = id >> 11, h = id & 2047;
    Xtl[xtl_off(b, I_ + h)] = 0;
  }
  if (id < B_ * I_) {
    int b = id >> 10, i = id & 1023;
    Xtl[xtl_off(b, i)] = input[(b * T_) * I_ + i] > 0.5f ? 1 : 0;
  }
  if (id < B_ * O_) {
    Om[id] = 0.f; Osp[id] = 0.f; Osu[id] = 0.f; Mo[id] = 0.f;
  }
  if (id < H_) {
    AlphaH[id] = (float)exp((double)(-1.0f / tau_h[id]));
  } else if (id < H_ + O_) {
    AlphaO[id - H_] = (float)exp((double)(-1.0f / tau_o[id - H_]));
  }
}

// ---------------------------------------------------------------------------
// Output phase for one batch (one block): r = h_spk @ w_ho^T in DOUBLE,
// single fp32 round, then fp32 program-order o_mem/spike/softmax.
// ---------------------------------------------------------------------------
__device__ __forceinline__ void ophase_block(
    int b, const int8_t* __restrict__ Xtl, const float* __restrict__ w_ho,
    const float* __restrict__ AlphaO, float* __restrict__ Om,
    float* __restrict__ Osp, float* __restrict__ Osu, float* __restrict__ Mo,
    float* r_lds, float* om_l, float* out, int fin) {
  const int tid = threadIdx.x;
  const int lane = tid & 63, wv = tid >> 6;
  float sv[32];
#pragma unroll
  for (int ii = 0; ii < 32; ++ii)
    sv[ii] = (float)Xtl[xtl_off(b, I_ + lane + ii * 64)];  // exact 0/1
#pragma unroll
  for (int oi = 0; oi < 5; ++oi) {
    int o = wv * 5 + oi;
    const float* wr = w_ho + o * H_;
    double s = 0.0;
#pragma unroll
    for (int ii = 0; ii < 32; ++ii)
      s += (double)sv[ii] * (double)wr[lane + ii * 64];
#pragma unroll
    for (int off = 32; off > 0; off >>= 1) s += __shfl_down(s, off);
    if (lane == 0) r_lds[o] = (float)s;   // single rounding
  }
  __syncthreads();
  if (tid < O_) {
    float m = Om[b * O_ + tid] * AlphaO[tid] * (1.0f - Osp[b * O_ + tid]) +
              r_lds[tid];
    om_l[tid] = m;
  }
  __syncthreads();
  if (tid < O_) {
    float mx = om_l[0];
#pragma unroll
    for (int o = 1; o < O_; ++o) mx = fmaxf(mx, om_l[o]);
    float se = 0.f;
#pragma unroll
    for (int o = 0; o < O_; ++o) se += expf(om_l[o] - mx);
    float m = om_l[tid];
    float sp = (m - 0.3f) > 0.f ? 1.f : 0.f;
    Om[b * O_ + tid] = m;
    Osp[b * O_ + tid] = sp;
    float su = Osu[b * O_ + tid] + sp;
    Osu[b * O_ + tid] = su;
    float mo = Mo[b * O_ + tid] + expf(m - mx) / se;
    Mo[b * O_ + tid] = mo;
    if (fin) {
      out[b * O_ + tid] = su / 50.0f;
      out[B_ * O_ + b * O_ + tid] = mo;
    }
  }
  __syncthreads();
}

// ---------------------------------------------------------------------------
// GEMM step: 768 blocks. Swizzled decode: group g=(p,nt) shares blockIdx%8
// (same XCD); member m=(mt2,ks). Block tile 128x64, 4 waves 2x2, wave tile
// 64x32 = 4 A-frags x 2 B-frags x 8 MFMAs. Direct global->VGPR, no barriers.
// Blocks j<256 also run ophase(t-1) for batch j when do_o.
// ---------------------------------------------------------------------------
__global__ __launch_bounds__(256) void gemm_step(
    const int8_t* __restrict__ Xtl, const int8_t* __restrict__ Wtl,
    int* __restrict__ P, const float* __restrict__ w_ho,
    const float* __restrict__ AlphaO, float* __restrict__ Om,
    float* __restrict__ Osp, float* __restrict__ Osu, float* __restrict__ Mo,
    int do_o) {
  __shared__ float r_lds[O_];
  __shared__ float om_l[O_];
  const int j = blockIdx.x;
  if (do_o && j < B_)
    ophase_block(j, Xtl, w_ho, AlphaO, Om, Osp, Osu, Mo, r_lds, om_l,
                 nullptr, 0);

  const int g = ((j >> 6) << 3) | (j & 7);   // weight group (p,nt) [0,96)
  const int m = (j >> 3) & 7;                // member (mt2,ks) [0,8)
  const int p = g >> 5, nt = g & 31;
  const int mt2 = m >> 2, ks = m & 3;

  const int tid = threadIdx.x;
  const int l = tid & 63, wv = tid >> 6;
  const int wm = wv >> 1, wn = wv & 1;
  const int r = l & 15, q = l >> 4;

  // A: batch rows mt2*128 + wm*64 + [0,64); 12 k-slabs from ks*12.
  const int8_t* pa = Xtl + (size_t)((mt2 * 2 + wm) * KA_ + ks * 12) * SLAB +
                     r * 64 + q * 16;
  // B: cols nt*64 + wn*32 + [0,32).
  const int8_t* pb = Wtl + (size_t)(nt * KW_ + p * KA_ + ks * 12) * SLAB +
                     (wn * 32 + r) * 64 + q * 16;

  intx4 c[4][2];
#pragma unroll
  for (int f = 0; f < 4; ++f)
#pragma unroll
    for (int g2 = 0; g2 < 2; ++g2) c[f][g2] = (intx4){0, 0, 0, 0};

  intx4 a[4], bb[2];
#pragma unroll
  for (int f = 0; f < 4; ++f) a[f] = *(const intx4*)(pa + f * 1024);
#pragma unroll
  for (int g2 = 0; g2 < 2; ++g2) bb[g2] = *(const intx4*)(pb + g2 * 1024);

#pragma unroll 4
  for (int kx = 0; kx < 12; ++kx) {
    const int kn = (kx < 11) ? (kx + 1) : 11;   // clamp: last iter reloads
    const int8_t* qa = pa + kn * SLAB;
    const int8_t* qb = pb + kn * SLAB;
    intx4 na[4], nb[2];
#pragma unroll
    for (int f = 0; f < 4; ++f) na[f] = *(const intx4*)(qa + f * 1024);
#pragma unroll
    for (int g2 = 0; g2 < 2; ++g2) nb[g2] = *(const intx4*)(qb + g2 * 1024);
#pragma unroll
    for (int f = 0; f < 4; ++f) {
      c[f][0] = __builtin_amdgcn_mfma_i32_16x16x64_i8(a[f], bb[0], c[f][0], 0, 0, 0);
      c[f][1] = __builtin_amdgcn_mfma_i32_16x16x64_i8(a[f], bb[1], c[f][1], 0, 0, 0);
    }
#pragma unroll
    for (int f = 0; f < 4; ++f) a[f] = na[f];
    bb[0] = nb[0]; bb[1] = nb[1];
  }

  // epilogue: D col=lane&15, row=quad*4+jj. Partial plane pp=(p,ks).
  int* Pp = P + (p * 4 + ks) * BH;
  const int b0r = mt2 * 128 + wm * 64 + q * 4;
  const int h0 = nt * 64 + wn * 32 + r;
#pragma unroll
  for (int f = 0; f < 4; ++f)
#pragma unroll
    for (int jj = 0; jj < 4; ++jj) {
      Pp[(b0r + f * 16 + jj) * H_ + h0]      = c[f][0][jj];
      Pp[(b0r + f * 16 + jj) * H_ + h0 + 16] = c[f][1][jj];
    }
}

// ---------------------------------------------------------------------------
// Spike/decay/pack: S = exact recombination of 12 i32 partial planes; single
// fp32 round of S*2^-27; fp32 program-order decay + threshold. Packs t+1.
// ---------------------------------------------------------------------------
__global__ void spike_pack(const int* __restrict__ P, float* __restrict__ Hm,
                           int8_t* __restrict__ Xtl,
                           const float* __restrict__ AlphaH,
                           const float* __restrict__ input, int t) {
  int blk = blockIdx.x;
  int b = blk >> 3, hc = blk & 7;
  int h = hc * 256 + threadIdx.x;
  int idx = b * H_ + h;
  int v0 = 0, v1 = 0, v2 = 0;
#pragma unroll
  for (int ks = 0; ks < 4; ++ks) {
    v0 += P[ks * BH + idx];
    v1 += P[(4 + ks) * BH + idx];
    v2 += P[(8 + ks) * BH + idx];
  }
  long long S = (long long)v0 + 256LL * (long long)v1 + 65536LL * (long long)v2;
  float M = (float)((double)S * 7.450580596923828125e-9);  // * 2^-27
  float sp = (float)Xtl[xtl_off(b, I_ + h)];
  float hprev = Hm[idx];
  float hm = M + hprev * AlphaH[h] * (1.0f - sp);  // fp32 program order
  int8_t spk = (hm - 0.3f) > 0.f ? 1 : 0;
  Hm[idx] = hm;
  Xtl[xtl_off(b, I_ + h)] = spk;
  if (hc < 4 && (t + 1) < T_) {
    Xtl[xtl_off(b, h)] = input[(b * T_ + t + 1) * I_ + h] > 0.5f ? 1 : 0;
  }
}

// ---------------------------------------------------------------------------
// Final ophase (t=49) + output write.
// ---------------------------------------------------------------------------
__global__ void final_k(const int8_t* __restrict__ Xtl,
                        const float* __restrict__ w_ho,
                        const float* __restrict__ AlphaO, float* __restrict__ Om,
                        float* __restrict__ Osp, float* __restrict__ Osu,
                        float* __restrict__ Mo, float* __restrict__ out) {
  __shared__ float r_lds[O_];
  __shared__ float om_l[O_];
  ophase_block(blockIdx.x, Xtl, w_ho, AlphaO, Om, Osp, Osu, Mo, r_lds, om_l,
               out, 1);
}

// ---------------------------------------------------------------------------
extern "C" void kernel_launch(void* const* d_in, const int* in_sizes, int n_in,
                              void* d_out, int out_size, void* d_ws, size_t ws_size,
                              hipStream_t stream) {
  const float* input = (const float*)d_in[0];
  const float* w_ih  = (const float*)d_in[1];
  const float* w_hh  = (const float*)d_in[2];
  const float* w_ho  = (const float*)d_in[3];
  const float* tau_h = (const float*)d_in[4];
  const float* tau_o = (const float*)d_in[5];

  char* ws = (char*)d_ws;
  // layout (bytes):
  // Wtl   @ 0         18,874,368
  // Xtl   @ 18874368     786,432
  // P     @ 19660800  25,165,824  (12 planes x 2 MB)
  // Hm    @ 44826624   2,097,152
  // Om    @ 46923776      20,480
  // Osp   @ 46944256      20,480
  // Osu   @ 46964736      20,480
  // Mo    @ 46985216      20,480
  // AlphaH@ 47005696       8,192
  // AlphaO@ 47013888          80
  int8_t* Wtl    = (int8_t*)(ws);
  int8_t* Xtl    = (int8_t*)(ws + 18874368);
  int*    P      = (int*)(ws + 19660800);
  float*  Hm     = (float*)(ws + 44826624);
  float*  Om     = (float*)(ws + 46923776);
  float*  Osp    = (float*)(ws + 46944256);
  float*  Osu    = (float*)(ws + 46964736);
  float*  Mo     = (float*)(ws + 46985216);
  float*  AlphaH = (float*)(ws + 47005696);
  float*  AlphaO = (float*)(ws + 47013888);
  float*  out    = (float*)d_out;

  prep_w<<<2048 * 9, 256, 0, stream>>>(w_ih, w_hh, Wtl);
  init_k<<<2048, 256, 0, stream>>>(Hm, Om, Osp, Osu, Mo, Xtl, input, tau_h,
                                   tau_o, AlphaH, AlphaO);
  for (int t = 0; t < T_; ++t) {
    gemm_step<<<768, 256, 0, stream>>>(Xtl, Wtl, P, w_ho, AlphaO, Om, Osp,
                                       Osu, Mo, t > 0 ? 1 : 0);
    spike_pack<<<2048, 256, 0, stream>>>(P, Hm, Xtl, AlphaH, input, t);
  }
  final_k<<<256, 256, 0, stream>>>(Xtl, w_ho, AlphaO, Om, Osp, Osu, Mo, out);
}